// Round 1
// baseline (9643.356 us; speedup 1.0000x reference)
//
#include <hip/hip_runtime.h>

#define DEVINL __device__ __forceinline__

typedef __attribute__((ext_vector_type(4))) float f32x4;
typedef __attribute__((ext_vector_type(8))) short s16x8;
typedef __attribute__((ext_vector_type(4))) unsigned short u16x4;
typedef __attribute__((ext_vector_type(8))) unsigned short u16x8;

static constexpr int HDIM = 4000;    // hidden
static constexpr int G4   = 16000;   // 4*H
static constexpr int FD   = 1024;    // feature dim
static constexpr int LD0  = 5024;    // W_ih0 row stride
static constexpr int TT   = 31;      // timesteps computed
static constexpr int NJ   = 64 * 31; // (b,t) pairs

DEVINL float bf2f(unsigned short u) {
  unsigned v = (unsigned)u << 16;
  return __builtin_bit_cast(float, v);
}
DEVINL unsigned short f2bf(float x) {
  unsigned u = __builtin_bit_cast(unsigned, x);
  u += 0x7fffu + ((u >> 16) & 1u);          // RNE, no NaNs in this problem
  return (unsigned short)(u >> 16);
}
DEVINL float sigm(float x) { return 1.f / (1.f + __expf(-x)); }
DEVINL float tanh_(float x) { float e = __expf(2.f * x); return (e - 1.f) / (e + 1.f); }

DEVINL s16x8 ld8(const unsigned short* p) {
  u16x4 lo = *(const u16x4*)p;
  u16x4 hi = *(const u16x4*)(p + 16);
  s16x8 r;
  r[0] = (short)lo[0]; r[1] = (short)lo[1]; r[2] = (short)lo[2]; r[3] = (short)lo[3];
  r[4] = (short)hi[0]; r[5] = (short)hi[1]; r[6] = (short)hi[2]; r[7] = (short)hi[3];
  return r;
}

// A = W rows [row0..row0+16) of row-major [*, K]; B = Hb [64][K] bf16.
// acc[n0] accumulates the 16x16 tile vs batch columns n0*16..n0*16+15.
DEVINL void gemm16(const unsigned short* __restrict__ W,
                   const unsigned short* __restrict__ Hb,
                   int K, int kbeg, int kend, int lr, int lg, f32x4* acc) {
  const unsigned short* wp  = W  + (size_t)lr * K + 4 * lg + kbeg;
  const unsigned short* hp0 = Hb + (size_t)lr * K + 4 * lg + kbeg;
  const unsigned short* hp1 = hp0 + (size_t)16 * K;
  const unsigned short* hp2 = hp0 + (size_t)32 * K;
  const unsigned short* hp3 = hp0 + (size_t)48 * K;
  int nk = kend - kbeg;
  #pragma unroll 4
  for (int k = 0; k < nk; k += 32) {
    s16x8 a  = ld8(wp  + k);
    s16x8 b0 = ld8(hp0 + k);
    s16x8 b1 = ld8(hp1 + k);
    s16x8 b2 = ld8(hp2 + k);
    s16x8 b3 = ld8(hp3 + k);
    acc[0] = __builtin_amdgcn_mfma_f32_16x16x32_bf16(a, b0, acc[0], 0, 0, 0);
    acc[1] = __builtin_amdgcn_mfma_f32_16x16x32_bf16(a, b1, acc[1], 0, 0, 0);
    acc[2] = __builtin_amdgcn_mfma_f32_16x16x32_bf16(a, b2, acc[2], 0, 0, 0);
    acc[3] = __builtin_amdgcn_mfma_f32_16x16x32_bf16(a, b3, acc[3], 0, 0, 0);
  }
}

__global__ void to_bf16_k(const float* __restrict__ s, unsigned short* __restrict__ d, long n) {
  long i = (((long)blockIdx.x * blockDim.x) + threadIdx.x) * 8;
  if (i >= n) return;
  f32x4 a = *(const f32x4*)(s + i);
  f32x4 b = *(const f32x4*)(s + i + 4);
  u16x8 o;
  o[0] = f2bf(a[0]); o[1] = f2bf(a[1]); o[2] = f2bf(a[2]); o[3] = f2bf(a[3]);
  o[4] = f2bf(b[0]); o[5] = f2bf(b[1]); o[6] = f2bf(b[2]); o[7] = f2bf(b[3]);
  *(u16x8*)(d + i) = o;
}

// W_f = W_ih0[:, :1024] (strided rows) -> bf16 [16000][1024]
__global__ void wf_conv_k(const float* __restrict__ s, unsigned short* __restrict__ d) {
  int idx = blockIdx.x * blockDim.x + threadIdx.x;   // 16000*128
  int r = idx >> 7;
  int k8 = (idx & 127) << 3;
  const float* sp = s + (size_t)r * LD0 + k8;
  f32x4 a = *(const f32x4*)sp;
  f32x4 b = *(const f32x4*)(sp + 4);
  u16x8 o;
  o[0] = f2bf(a[0]); o[1] = f2bf(a[1]); o[2] = f2bf(a[2]); o[3] = f2bf(a[3]);
  o[4] = f2bf(b[0]); o[5] = f2bf(b[1]); o[6] = f2bf(b[2]); o[7] = f2bf(b[3]);
  *(u16x8*)(d + (size_t)r * FD + k8) = o;
}

// fp0[b][r] = b_ih0[r] + sum_k feat[b][k] * Wf[r][k]
__global__ __launch_bounds__(512, 2) void featpre_k(
    const unsigned short* __restrict__ Wf, const unsigned short* __restrict__ Fb,
    const float* __restrict__ bih0, float* __restrict__ fp0) {
  __shared__ float gl[2][4][16][64];
  int tid = threadIdx.x, lane = tid & 63, wid = tid >> 6;
  int lr = lane & 15, lg = lane >> 4;
  int sub = wid & 3, kh = wid >> 2;
  int rowblk = blockIdx.x << 6;
  size_t row0 = (size_t)rowblk + (sub << 4);
  f32x4 acc[4] = {};
  gemm16(Wf + row0 * FD, Fb, FD, kh ? 512 : 0, kh ? 1024 : 512, lr, lg, acc);
  #pragma unroll
  for (int n0 = 0; n0 < 4; ++n0)
    #pragma unroll
    for (int e = 0; e < 4; ++e)
      gl[kh][sub][4 * lg + e][(n0 << 4) + lr] = acc[n0][e];
  __syncthreads();
  for (int n = tid; n < 4096; n += 512) {
    int i = n & 63, b = n >> 6;
    int r = rowblk + i;
    float v = gl[0][i >> 4][i & 15][b] + gl[1][i >> 4][i & 15][b] + bih0[r];
    fp0[(size_t)b * G4 + r] = v;
  }
}

// ih0[b*31+t][r] = bf16( fp0[b][r] + W_v[r][tok(b,t)] ), W_v read once via LDS rows
__global__ __launch_bounds__(256) void gather_k(
    const float* __restrict__ Wih0, const int* __restrict__ caps,
    const float* __restrict__ fp0, unsigned short* __restrict__ ih0) {
  __shared__ float wv[4][4000];
  int r0 = blockIdx.x << 2;
  for (int rr = 0; rr < 4; ++rr)
    for (int c = threadIdx.x; c < 4000; c += 256)
      wv[rr][c] = Wih0[(size_t)(r0 + rr) * LD0 + FD + c];
  __syncthreads();
  for (int j = threadIdx.x; j < NJ; j += 256) {
    int b = j / TT, t = j - b * TT;
    int tok = caps[(b << 5) + t];
    f32x4 f = *(const f32x4*)(fp0 + (size_t)b * G4 + r0);
    u16x4 o;
    o[0] = f2bf(f[0] + wv[0][tok]);
    o[1] = f2bf(f[1] + wv[1][tok]);
    o[2] = f2bf(f[2] + wv[2][tok]);
    o[3] = f2bf(f[3] + wv[3][tok]);
    *(u16x4*)(ih0 + (size_t)j * G4 + r0) = o;
  }
}

__global__ __launch_bounds__(512, 2) void lstm_l0_k(
    const unsigned short* __restrict__ Whh0, const unsigned short* __restrict__ h_in,
    unsigned short* __restrict__ h_out, float* __restrict__ c0,
    const unsigned short* __restrict__ ih0, const float* __restrict__ bhh0, int t) {
  __shared__ float gl[2][4][16][64];
  int tid = threadIdx.x, lane = tid & 63, wid = tid >> 6;
  int lr = lane & 15, lg = lane >> 4;
  int gate = wid & 3, kh = wid >> 2;
  int wg16 = blockIdx.x << 4;
  size_t row0 = (size_t)gate * HDIM + wg16;
  f32x4 acc[4] = {};
  int kbeg = kh ? 2016 : 0, kend = kh ? 4000 : 2016;   // 32-aligned halves of K=4000
  gemm16(Whh0 + row0 * HDIM, h_in, HDIM, kbeg, kend, lr, lg, acc);
  #pragma unroll
  for (int n0 = 0; n0 < 4; ++n0)
    #pragma unroll
    for (int e = 0; e < 4; ++e)
      gl[kh][gate][4 * lg + e][(n0 << 4) + lr] = acc[n0][e];
  __syncthreads();
  for (int n = tid; n < 1024; n += 512) {
    int i = n & 15, b = n >> 4;
    int r = wg16 + i;
    const unsigned short* ih = ih0 + (size_t)(b * TT + t) * G4;
    float gi = gl[0][0][i][b] + gl[1][0][i][b] + bf2f(ih[r])             + bhh0[r];
    float gf = gl[0][1][i][b] + gl[1][1][i][b] + bf2f(ih[HDIM + r])      + bhh0[HDIM + r];
    float gg = gl[0][2][i][b] + gl[1][2][i][b] + bf2f(ih[2 * HDIM + r])  + bhh0[2 * HDIM + r];
    float go = gl[0][3][i][b] + gl[1][3][i][b] + bf2f(ih[3 * HDIM + r])  + bhh0[3 * HDIM + r];
    size_t ci = (size_t)b * HDIM + r;
    float cn = sigm(gf) * c0[ci] + sigm(gi) * tanh_(gg);
    float hn = sigm(go) * tanh_(cn);
    c0[ci] = cn;
    h_out[ci] = f2bf(hn);
  }
}

__global__ __launch_bounds__(512, 2) void lstm_l1_k(
    const unsigned short* __restrict__ Wih1, const unsigned short* __restrict__ Whh1,
    const unsigned short* __restrict__ h0, const unsigned short* __restrict__ h1_in,
    unsigned short* __restrict__ h1_out, float* __restrict__ c1,
    const float* __restrict__ bih1, const float* __restrict__ bhh1,
    float* __restrict__ out, int t) {
  __shared__ float gl[2][4][16][64];
  int tid = threadIdx.x, lane = tid & 63, wid = tid >> 6;
  int lr = lane & 15, lg = lane >> 4;
  int gate = wid & 3, kh = wid >> 2;
  int wg16 = blockIdx.x << 4;
  size_t row0 = (size_t)gate * HDIM + wg16;
  f32x4 acc[4] = {};
  int kbeg = kh ? 2016 : 0, kend = kh ? 4000 : 2016;
  gemm16(Wih1 + row0 * HDIM, h0,    HDIM, kbeg, kend, lr, lg, acc);
  gemm16(Whh1 + row0 * HDIM, h1_in, HDIM, kbeg, kend, lr, lg, acc);
  #pragma unroll
  for (int n0 = 0; n0 < 4; ++n0)
    #pragma unroll
    for (int e = 0; e < 4; ++e)
      gl[kh][gate][4 * lg + e][(n0 << 4) + lr] = acc[n0][e];
  __syncthreads();
  for (int n = tid; n < 1024; n += 512) {
    int i = n & 15, b = n >> 4;
    int r = wg16 + i;
    float gi = gl[0][0][i][b] + gl[1][0][i][b] + bih1[r]            + bhh1[r];
    float gf = gl[0][1][i][b] + gl[1][1][i][b] + bih1[HDIM + r]     + bhh1[HDIM + r];
    float gg = gl[0][2][i][b] + gl[1][2][i][b] + bih1[2 * HDIM + r] + bhh1[2 * HDIM + r];
    float go = gl[0][3][i][b] + gl[1][3][i][b] + bih1[3 * HDIM + r] + bhh1[3 * HDIM + r];
    size_t ci = (size_t)b * HDIM + r;
    float cn = sigm(gf) * c1[ci] + sigm(gi) * tanh_(gg);
    float hn = sigm(go) * tanh_(cn);
    c1[ci] = cn;
    h1_out[ci] = f2bf(hn);
    out[(size_t)b * (32 * HDIM) + (size_t)(t + 1) * HDIM + r] = hn;
  }
}

__global__ void sentinel_k(float* o) { o[0] = -123456.f; }

extern "C" void kernel_launch(void* const* d_in, const int* in_sizes, int n_in,
                              void* d_out, int out_size, void* d_ws, size_t ws_size,
                              hipStream_t stream) {
  (void)in_sizes; (void)n_in;
  const float* features = (const float*)d_in[0];
  const int*   captions = (const int*)d_in[1];
  const float* W_ih0    = (const float*)d_in[2];
  const float* W_hh0    = (const float*)d_in[3];
  const float* b_ih0    = (const float*)d_in[4];
  const float* b_hh0    = (const float*)d_in[5];
  const float* W_ih1    = (const float*)d_in[6];
  const float* W_hh1    = (const float*)d_in[7];
  const float* b_ih1    = (const float*)d_in[8];
  const float* b_hh1    = (const float*)d_in[9];
  float* out = (float*)d_out;

  char* w = (char*)d_ws;
  // state (memset region) first
  unsigned short* h0b   = (unsigned short*)(w);                 // 2 x 256000 elems
  unsigned short* h1b   = (unsigned short*)(w + 1024000);       // 2 x 256000 elems
  float*          c0    = (float*)(w + 2048000);
  float*          c1    = (float*)(w + 3072000);
  unsigned short* bWhh0 = (unsigned short*)(w + 4096000);
  unsigned short* bWih1 = (unsigned short*)(w + 132096000);
  unsigned short* bWhh1 = (unsigned short*)(w + 260096000);
  unsigned short* bWf   = (unsigned short*)(w + 388096000);
  unsigned short* ih0   = (unsigned short*)(w + 420864000);
  float*          fp0   = (float*)(w + 484352000);
  unsigned short* bFeat = (unsigned short*)(w + 488448000);
  const size_t NEED = 488579072;
  if (ws_size < NEED) { sentinel_k<<<1, 1, 0, stream>>>(out); return; }

  hipMemsetAsync(d_out, 0, (size_t)out_size * 4, stream);  // also provides out[:,0,:]=0
  hipMemsetAsync(w, 0, 4096000, stream);                   // h/c initial state = 0

  to_bf16_k<<<31250, 256, 0, stream>>>(W_hh0, bWhh0, 64000000L);
  to_bf16_k<<<31250, 256, 0, stream>>>(W_ih1, bWih1, 64000000L);
  to_bf16_k<<<31250, 256, 0, stream>>>(W_hh1, bWhh1, 64000000L);
  to_bf16_k<<<32,    256, 0, stream>>>(features, bFeat, 65536L);
  wf_conv_k<<<8000,  256, 0, stream>>>(W_ih0, bWf);
  featpre_k<<<250,   512, 0, stream>>>(bWf, bFeat, b_ih0, fp0);
  gather_k<<<4000,   256, 0, stream>>>(W_ih0, captions, fp0, ih0);

  for (int t = 0; t < TT; ++t) {
    unsigned short* h0_in  = h0b + (size_t)(t & 1) * 256000;
    unsigned short* h0_out = h0b + (size_t)((t + 1) & 1) * 256000;
    unsigned short* h1_in  = h1b + (size_t)(t & 1) * 256000;
    unsigned short* h1_out = h1b + (size_t)((t + 1) & 1) * 256000;
    lstm_l0_k<<<250, 512, 0, stream>>>(bWhh0, h0_in, h0_out, c0, ih0, b_hh0, t);
    lstm_l1_k<<<250, 512, 0, stream>>>(bWih1, bWhh1, h0_out, h1_in, h1_out, c1,
                                       b_ih1, b_hh1, out, t);
  }
}

// Round 2
// 7161.921 us; speedup vs baseline: 1.3465x; 1.3465x over previous
//
#include <hip/hip_runtime.h>

#define DEVINL __device__ __forceinline__

typedef __attribute__((ext_vector_type(4))) float f32x4;
typedef __attribute__((ext_vector_type(8))) short s16x8;
typedef __attribute__((ext_vector_type(4))) unsigned short u16x4;
typedef __attribute__((ext_vector_type(8))) unsigned short u16x8;

static constexpr int HDIM = 4000;    // hidden
static constexpr int G4   = 16000;   // 4*H
static constexpr int FD   = 1024;    // feature dim
static constexpr int LD0  = 5024;    // W_ih0 row stride
static constexpr int TT   = 31;      // timesteps computed
static constexpr int NJ   = 64 * 31; // (b,t) pairs

DEVINL float bf2f(unsigned short u) {
  unsigned v = (unsigned)u << 16;
  return __builtin_bit_cast(float, v);
}
DEVINL unsigned short f2bf(float x) {
  unsigned u = __builtin_bit_cast(unsigned, x);
  u += 0x7fffu + ((u >> 16) & 1u);          // RNE, no NaNs in this problem
  return (unsigned short)(u >> 16);
}
DEVINL float sigm(float x) { return 1.f / (1.f + __expf(-x)); }
DEVINL float tanh_(float x) { float e = __expf(2.f * x); return (e - 1.f) / (e + 1.f); }

// A = W rows [row0..row0+16) of row-major [*, K]; B = Hb [64][K] bf16.
// Fragment k-mapping: element (lg, j) <-> k = 8*lg + j. Any consistent
// permutation of k cancels between A and B operands, so a single contiguous
// 16B load per fragment is valid. acc[n0] = 16x16 tile vs batch cols n0*16+..
DEVINL void gemm16(const unsigned short* __restrict__ W,
                   const unsigned short* __restrict__ Hb,
                   int K, int kbeg, int kend, int lr, int lg, f32x4* acc) {
  const unsigned short* wp  = W  + (size_t)lr * K + 8 * lg + kbeg;
  const unsigned short* hp0 = Hb + (size_t)lr * K + 8 * lg + kbeg;
  const unsigned short* hp1 = hp0 + (size_t)16 * K;
  const unsigned short* hp2 = hp0 + (size_t)32 * K;
  const unsigned short* hp3 = hp0 + (size_t)48 * K;
  int nk = kend - kbeg;
  #pragma unroll 2
  for (int k = 0; k < nk; k += 32) {
    s16x8 a  = *(const s16x8*)(wp  + k);
    s16x8 b0 = *(const s16x8*)(hp0 + k);
    s16x8 b1 = *(const s16x8*)(hp1 + k);
    s16x8 b2 = *(const s16x8*)(hp2 + k);
    s16x8 b3 = *(const s16x8*)(hp3 + k);
    acc[0] = __builtin_amdgcn_mfma_f32_16x16x32_bf16(a, b0, acc[0], 0, 0, 0);
    acc[1] = __builtin_amdgcn_mfma_f32_16x16x32_bf16(a, b1, acc[1], 0, 0, 0);
    acc[2] = __builtin_amdgcn_mfma_f32_16x16x32_bf16(a, b2, acc[2], 0, 0, 0);
    acc[3] = __builtin_amdgcn_mfma_f32_16x16x32_bf16(a, b3, acc[3], 0, 0, 0);
  }
}

__global__ void to_bf16_k(const float* __restrict__ s, unsigned short* __restrict__ d, long n) {
  long i = (((long)blockIdx.x * blockDim.x) + threadIdx.x) * 8;
  if (i >= n) return;
  f32x4 a = *(const f32x4*)(s + i);
  f32x4 b = *(const f32x4*)(s + i + 4);
  u16x8 o;
  o[0] = f2bf(a[0]); o[1] = f2bf(a[1]); o[2] = f2bf(a[2]); o[3] = f2bf(a[3]);
  o[4] = f2bf(b[0]); o[5] = f2bf(b[1]); o[6] = f2bf(b[2]); o[7] = f2bf(b[3]);
  *(u16x8*)(d + i) = o;
}

// W_f = W_ih0[:, :1024] (strided rows) -> bf16 [16000][1024]
__global__ void wf_conv_k(const float* __restrict__ s, unsigned short* __restrict__ d) {
  int idx = blockIdx.x * blockDim.x + threadIdx.x;   // 16000*128
  int r = idx >> 7;
  int k8 = (idx & 127) << 3;
  const float* sp = s + (size_t)r * LD0 + k8;
  f32x4 a = *(const f32x4*)sp;
  f32x4 b = *(const f32x4*)(sp + 4);
  u16x8 o;
  o[0] = f2bf(a[0]); o[1] = f2bf(a[1]); o[2] = f2bf(a[2]); o[3] = f2bf(a[3]);
  o[4] = f2bf(b[0]); o[5] = f2bf(b[1]); o[6] = f2bf(b[2]); o[7] = f2bf(b[3]);
  *(u16x8*)(d + (size_t)r * FD + k8) = o;
}

// fp0[b][r] = b_ih0[r] + sum_k feat[b][k] * Wf[r][k]
__global__ __launch_bounds__(512, 2) void featpre_k(
    const unsigned short* __restrict__ Wf, const unsigned short* __restrict__ Fb,
    const float* __restrict__ bih0, float* __restrict__ fp0) {
  __shared__ float gl[2][4][16][64];
  int tid = threadIdx.x, lane = tid & 63, wid = tid >> 6;
  int lr = lane & 15, lg = lane >> 4;
  int sub = wid & 3, kh = wid >> 2;
  int rowblk = blockIdx.x << 6;
  size_t row0 = (size_t)rowblk + (sub << 4);
  f32x4 acc[4] = {};
  gemm16(Wf + row0 * FD, Fb, FD, kh ? 512 : 0, kh ? 1024 : 512, lr, lg, acc);
  #pragma unroll
  for (int n0 = 0; n0 < 4; ++n0)
    #pragma unroll
    for (int e = 0; e < 4; ++e)
      gl[kh][sub][4 * lg + e][(n0 << 4) + lr] = acc[n0][e];
  __syncthreads();
  for (int n = tid; n < 4096; n += 512) {
    int i = n & 63, b = n >> 6;
    int r = rowblk + i;
    float v = gl[0][i >> 4][i & 15][b] + gl[1][i >> 4][i & 15][b] + bih0[r];
    fp0[(size_t)b * G4 + r] = v;
  }
}

// ih0T[r][j] = bf16( fp0[b][r] + W_v[r][tok(b,t)] ), j = b*31+t. Coalesced writes.
__global__ __launch_bounds__(256) void gather_k(
    const float* __restrict__ Wih0, const int* __restrict__ caps,
    const float* __restrict__ fp0, unsigned short* __restrict__ ih0T) {
  __shared__ float wv[4][4000];
  int r0 = blockIdx.x << 2;
  for (int rr = 0; rr < 4; ++rr)
    for (int c = threadIdx.x; c < 4000; c += 256)
      wv[rr][c] = Wih0[(size_t)(r0 + rr) * LD0 + FD + c];
  __syncthreads();
  for (int j = threadIdx.x; j < NJ; j += 256) {
    int b = j / TT, t = j - b * TT;
    int tok = caps[(b << 5) + t];
    f32x4 f = *(const f32x4*)(fp0 + (size_t)b * G4 + r0);
    #pragma unroll
    for (int rr = 0; rr < 4; ++rr)
      ih0T[(size_t)(r0 + rr) * NJ + j] = f2bf(f[rr] + wv[rr][tok]);
  }
}

__global__ __launch_bounds__(1024, 4) void lstm_l0_k(
    const unsigned short* __restrict__ Whh0, const unsigned short* __restrict__ h_in,
    unsigned short* __restrict__ h_out, float* __restrict__ c0,
    const unsigned short* __restrict__ ih0T, const float* __restrict__ bhh0, int t) {
  __shared__ float gl[2][4][16][64];
  int tid = threadIdx.x, lane = tid & 63, wid = tid >> 6;   // wid 0..15
  int lr = lane & 15, lg = lane >> 4;
  int gate = wid & 3, kq = wid >> 2;                        // 4-way K split
  int wg16 = blockIdx.x << 4;
  size_t row0 = (size_t)gate * HDIM + wg16;
  int kbeg = kq << 10;
  int kend = (kq == 3) ? 4000 : kbeg + 1024;                // 32-aligned chunks
  f32x4 acc[4] = {};
  gemm16(Whh0 + row0 * HDIM, h_in, HDIM, kbeg, kend, lr, lg, acc);
  if (kq < 2) {
    #pragma unroll
    for (int n0 = 0; n0 < 4; ++n0)
      #pragma unroll
      for (int e = 0; e < 4; ++e)
        gl[kq][gate][4 * lg + e][(n0 << 4) + lr] = acc[n0][e];
  }
  __syncthreads();
  if (kq >= 2) {
    #pragma unroll
    for (int n0 = 0; n0 < 4; ++n0)
      #pragma unroll
      for (int e = 0; e < 4; ++e)
        gl[kq - 2][gate][4 * lg + e][(n0 << 4) + lr] += acc[n0][e];
  }
  __syncthreads();
  int i = tid & 15, b = tid >> 4;                           // 1024 = 16 x 64
  int r = wg16 + i;
  size_t jo = (size_t)b * TT + t;
  float gi = gl[0][0][i][b] + gl[1][0][i][b] + bf2f(ih0T[(size_t)r * NJ + jo])              + bhh0[r];
  float gf = gl[0][1][i][b] + gl[1][1][i][b] + bf2f(ih0T[(size_t)(HDIM + r) * NJ + jo])     + bhh0[HDIM + r];
  float gg = gl[0][2][i][b] + gl[1][2][i][b] + bf2f(ih0T[(size_t)(2 * HDIM + r) * NJ + jo]) + bhh0[2 * HDIM + r];
  float go = gl[0][3][i][b] + gl[1][3][i][b] + bf2f(ih0T[(size_t)(3 * HDIM + r) * NJ + jo]) + bhh0[3 * HDIM + r];
  size_t ci = (size_t)b * HDIM + r;
  float cn = sigm(gf) * c0[ci] + sigm(gi) * tanh_(gg);
  float hn = sigm(go) * tanh_(cn);
  c0[ci] = cn;
  h_out[ci] = f2bf(hn);
}

__global__ __launch_bounds__(1024, 4) void lstm_l1_k(
    const unsigned short* __restrict__ Wih1, const unsigned short* __restrict__ Whh1,
    const unsigned short* __restrict__ h0, const unsigned short* __restrict__ h1_in,
    unsigned short* __restrict__ h1_out, float* __restrict__ c1,
    const float* __restrict__ bih1, const float* __restrict__ bhh1,
    float* __restrict__ out, int t) {
  __shared__ float gl[2][4][16][64];
  int tid = threadIdx.x, lane = tid & 63, wid = tid >> 6;
  int lr = lane & 15, lg = lane >> 4;
  int gate = wid & 3, kq = wid >> 2;
  int wg16 = blockIdx.x << 4;
  size_t row0 = (size_t)gate * HDIM + wg16;
  int kbeg = kq << 10;
  int kend = (kq == 3) ? 4000 : kbeg + 1024;
  f32x4 acc[4] = {};
  gemm16(Wih1 + row0 * HDIM, h0,    HDIM, kbeg, kend, lr, lg, acc);
  gemm16(Whh1 + row0 * HDIM, h1_in, HDIM, kbeg, kend, lr, lg, acc);
  if (kq < 2) {
    #pragma unroll
    for (int n0 = 0; n0 < 4; ++n0)
      #pragma unroll
      for (int e = 0; e < 4; ++e)
        gl[kq][gate][4 * lg + e][(n0 << 4) + lr] = acc[n0][e];
  }
  __syncthreads();
  if (kq >= 2) {
    #pragma unroll
    for (int n0 = 0; n0 < 4; ++n0)
      #pragma unroll
      for (int e = 0; e < 4; ++e)
        gl[kq - 2][gate][4 * lg + e][(n0 << 4) + lr] += acc[n0][e];
  }
  __syncthreads();
  int i = tid & 15, b = tid >> 4;
  int r = wg16 + i;
  float gi = gl[0][0][i][b] + gl[1][0][i][b] + bih1[r]            + bhh1[r];
  float gf = gl[0][1][i][b] + gl[1][1][i][b] + bih1[HDIM + r]     + bhh1[HDIM + r];
  float gg = gl[0][2][i][b] + gl[1][2][i][b] + bih1[2 * HDIM + r] + bhh1[2 * HDIM + r];
  float go = gl[0][3][i][b] + gl[1][3][i][b] + bih1[3 * HDIM + r] + bhh1[3 * HDIM + r];
  size_t ci = (size_t)b * HDIM + r;
  float cn = sigm(gf) * c1[ci] + sigm(gi) * tanh_(gg);
  float hn = sigm(go) * tanh_(cn);
  c1[ci] = cn;
  h1_out[ci] = f2bf(hn);
  out[(size_t)b * (32 * HDIM) + (size_t)(t + 1) * HDIM + r] = hn;
}

__global__ void sentinel_k(float* o) { o[0] = -123456.f; }

extern "C" void kernel_launch(void* const* d_in, const int* in_sizes, int n_in,
                              void* d_out, int out_size, void* d_ws, size_t ws_size,
                              hipStream_t stream) {
  (void)in_sizes; (void)n_in;
  const float* features = (const float*)d_in[0];
  const int*   captions = (const int*)d_in[1];
  const float* W_ih0    = (const float*)d_in[2];
  const float* W_hh0    = (const float*)d_in[3];
  const float* b_ih0    = (const float*)d_in[4];
  const float* b_hh0    = (const float*)d_in[5];
  const float* W_ih1    = (const float*)d_in[6];
  const float* W_hh1    = (const float*)d_in[7];
  const float* b_ih1    = (const float*)d_in[8];
  const float* b_hh1    = (const float*)d_in[9];
  float* out = (float*)d_out;

  char* w = (char*)d_ws;
  // state (memset region) first
  unsigned short* h0b   = (unsigned short*)(w);                 // 2 x 256000 elems
  unsigned short* h1b   = (unsigned short*)(w + 1024000);       // 2 x 256000 elems
  float*          c0    = (float*)(w + 2048000);
  float*          c1    = (float*)(w + 3072000);
  unsigned short* bWhh0 = (unsigned short*)(w + 4096000);
  unsigned short* bWih1 = (unsigned short*)(w + 132096000);
  unsigned short* bWhh1 = (unsigned short*)(w + 260096000);
  unsigned short* bWf   = (unsigned short*)(w + 388096000);
  unsigned short* ih0T  = (unsigned short*)(w + 420864000);     // [16000][1984] bf16
  float*          fp0   = (float*)(w + 484352000);
  unsigned short* bFeat = (unsigned short*)(w + 488448000);
  const size_t NEED = 488579072;
  if (ws_size < NEED) { sentinel_k<<<1, 1, 0, stream>>>(out); return; }

  hipMemsetAsync(d_out, 0, (size_t)out_size * 4, stream);  // also provides out[:,0,:]=0
  hipMemsetAsync(w, 0, 4096000, stream);                   // h/c initial state = 0

  to_bf16_k<<<31250, 256, 0, stream>>>(W_hh0, bWhh0, 64000000L);
  to_bf16_k<<<31250, 256, 0, stream>>>(W_ih1, bWih1, 64000000L);
  to_bf16_k<<<31250, 256, 0, stream>>>(W_hh1, bWhh1, 64000000L);
  to_bf16_k<<<32,    256, 0, stream>>>(features, bFeat, 65536L);
  wf_conv_k<<<8000,  256, 0, stream>>>(W_ih0, bWf);
  featpre_k<<<250,   512, 0, stream>>>(bWf, bFeat, b_ih0, fp0);
  gather_k<<<4000,   256, 0, stream>>>(W_ih0, captions, fp0, ih0T);

  for (int t = 0; t < TT; ++t) {
    unsigned short* h0_in  = h0b + (size_t)(t & 1) * 256000;
    unsigned short* h0_out = h0b + (size_t)((t + 1) & 1) * 256000;
    unsigned short* h1_in  = h1b + (size_t)(t & 1) * 256000;
    unsigned short* h1_out = h1b + (size_t)((t + 1) & 1) * 256000;
    lstm_l0_k<<<250, 1024, 0, stream>>>(bWhh0, h0_in, h0_out, c0, ih0T, b_hh0, t);
    lstm_l1_k<<<250, 1024, 0, stream>>>(bWih1, bWhh1, h0_out, h1_in, h1_out, c1,
                                        b_ih1, b_hh1, out, t);
  }
}

// Round 3
// 4011.308 us; speedup vs baseline: 2.4040x; 1.7854x over previous
//
#include <hip/hip_runtime.h>

#define DEVINL __device__ __forceinline__

typedef __attribute__((ext_vector_type(4))) float f32x4;
typedef __attribute__((ext_vector_type(8))) short s16x8;
typedef __attribute__((ext_vector_type(4))) unsigned short u16x4;
typedef __attribute__((ext_vector_type(8))) unsigned short u16x8;

static constexpr int HDIM = 4000;    // hidden
static constexpr int G4   = 16000;   // 4*H
static constexpr int FD   = 1024;    // feature dim
static constexpr int LD0  = 5024;    // W_ih0 row stride
static constexpr int TT   = 31;      // timesteps computed
static constexpr int NJ   = 64 * 31; // (b,t) pairs
static constexpr int KCT  = 125;     // k-chunks (32 wide) per K=4000

DEVINL float bf2f(unsigned short u) {
  unsigned v = (unsigned)u << 16;
  return __builtin_bit_cast(float, v);
}
DEVINL unsigned short f2bf(float x) {
  unsigned u = __builtin_bit_cast(unsigned, x);
  u += 0x7fffu + ((u >> 16) & 1u);          // RNE, no NaNs in this problem
  return (unsigned short)(u >> 16);
}
DEVINL float sigm(float x) { return 1.f / (1.f + __expf(-x)); }
DEVINL float tanh_(float x) { float e = __expf(2.f * x); return (e - 1.f) / (e + 1.f); }

// ---------- packed-layout GEMM ----------
// A: pW chunk layout [o][lane][8], o = (rb*4+g)*125 + kc; element (o,lane,e) =
//    W[g*4000+rb*16+(lane&15)][kc*32+(lane>>4)*8+e].  1 KB/instr, sequential.
// B: hP layout [k8][64][8]; frag n0 at ((kc*4+lg)*64 + n0*16 + lr)*8 — the 4
//    frags of one iter form one contiguous 4 KB span (L1-friendly).
// k-permutation (k = 8*lg+e within chunk) is identical on A and B -> cancels.
DEVINL void gemmP(const unsigned short* __restrict__ Wp,
                  const unsigned short* __restrict__ hP,
                  int kc0, int kc1, int lane, int lr, int lg, f32x4* acc) {
  const unsigned short* wp = Wp + (size_t)kc0 * 512 + lane * 8;
  const unsigned short* bp = hP + (size_t)kc0 * 2048 + (lg * 64 + lr) * 8;
  #pragma unroll 2
  for (int kc = kc0; kc < kc1; ++kc) {
    s16x8 a  = *(const s16x8*)wp;
    s16x8 b0 = *(const s16x8*)(bp);
    s16x8 b1 = *(const s16x8*)(bp + 128);
    s16x8 b2 = *(const s16x8*)(bp + 256);
    s16x8 b3 = *(const s16x8*)(bp + 384);
    wp += 512; bp += 2048;
    acc[0] = __builtin_amdgcn_mfma_f32_16x16x32_bf16(a, b0, acc[0], 0, 0, 0);
    acc[1] = __builtin_amdgcn_mfma_f32_16x16x32_bf16(a, b1, acc[1], 0, 0, 0);
    acc[2] = __builtin_amdgcn_mfma_f32_16x16x32_bf16(a, b2, acc[2], 0, 0, 0);
    acc[3] = __builtin_amdgcn_mfma_f32_16x16x32_bf16(a, b3, acc[3], 0, 0, 0);
  }
}

// ---------- old-style GEMM (featpre only; B = [64][K] row-major) ----------
DEVINL void gemm16u(const unsigned short* __restrict__ W,
                    const unsigned short* __restrict__ Hb,
                    int K, int kbeg, int kend, int lr, int lg, f32x4* acc) {
  const unsigned short* wp  = W  + (size_t)lr * K + 8 * lg + kbeg;
  const unsigned short* hp0 = Hb + (size_t)lr * K + 8 * lg + kbeg;
  const unsigned short* hp1 = hp0 + (size_t)16 * K;
  const unsigned short* hp2 = hp0 + (size_t)32 * K;
  const unsigned short* hp3 = hp0 + (size_t)48 * K;
  int nk = kend - kbeg;
  #pragma unroll 2
  for (int k = 0; k < nk; k += 32) {
    s16x8 a  = *(const s16x8*)(wp  + k);
    s16x8 b0 = *(const s16x8*)(hp0 + k);
    s16x8 b1 = *(const s16x8*)(hp1 + k);
    s16x8 b2 = *(const s16x8*)(hp2 + k);
    s16x8 b3 = *(const s16x8*)(hp3 + k);
    acc[0] = __builtin_amdgcn_mfma_f32_16x16x32_bf16(a, b0, acc[0], 0, 0, 0);
    acc[1] = __builtin_amdgcn_mfma_f32_16x16x32_bf16(a, b1, acc[1], 0, 0, 0);
    acc[2] = __builtin_amdgcn_mfma_f32_16x16x32_bf16(a, b2, acc[2], 0, 0, 0);
    acc[3] = __builtin_amdgcn_mfma_f32_16x16x32_bf16(a, b3, acc[3], 0, 0, 0);
  }
}

__global__ void to_bf16_k(const float* __restrict__ s, unsigned short* __restrict__ d, long n) {
  long i = (((long)blockIdx.x * blockDim.x) + threadIdx.x) * 8;
  if (i >= n) return;
  f32x4 a = *(const f32x4*)(s + i);
  f32x4 b = *(const f32x4*)(s + i + 4);
  u16x8 o;
  o[0] = f2bf(a[0]); o[1] = f2bf(a[1]); o[2] = f2bf(a[2]); o[3] = f2bf(a[3]);
  o[4] = f2bf(b[0]); o[5] = f2bf(b[1]); o[6] = f2bf(b[2]); o[7] = f2bf(b[3]);
  *(u16x8*)(d + i) = o;
}

// pack W [16000][4000] f32 -> fragment-linear bf16 chunks
__global__ __launch_bounds__(256) void pack_k(const float* __restrict__ W,
                                              unsigned short* __restrict__ P) {
  int wv = (blockIdx.x << 2) + (threadIdx.x >> 6);    // chunk id 0..124999
  int lane = threadIdx.x & 63, lr = lane & 15, lg = lane >> 4;
  int rb = wv / 500; int rem = wv - rb * 500;
  int g = rem / KCT; int kc = rem - g * KCT;
  int row = g * 4000 + rb * 16 + lr;
  int col = kc * 32 + lg * 8;
  const float* sp = W + (size_t)row * 4000 + col;
  f32x4 a = *(const f32x4*)sp;
  f32x4 b = *(const f32x4*)(sp + 4);
  u16x8 o;
  o[0] = f2bf(a[0]); o[1] = f2bf(a[1]); o[2] = f2bf(a[2]); o[3] = f2bf(a[3]);
  o[4] = f2bf(b[0]); o[5] = f2bf(b[1]); o[6] = f2bf(b[2]); o[7] = f2bf(b[3]);
  *(u16x8*)(P + ((size_t)wv * 64 + lane) * 8) = o;
}

// W_f = W_ih0[:, :1024] (strided rows) -> bf16 [16000][1024]
__global__ void wf_conv_k(const float* __restrict__ s, unsigned short* __restrict__ d) {
  int idx = blockIdx.x * blockDim.x + threadIdx.x;   // 16000*128
  int r = idx >> 7;
  int k8 = (idx & 127) << 3;
  const float* sp = s + (size_t)r * LD0 + k8;
  f32x4 a = *(const f32x4*)sp;
  f32x4 b = *(const f32x4*)(sp + 4);
  u16x8 o;
  o[0] = f2bf(a[0]); o[1] = f2bf(a[1]); o[2] = f2bf(a[2]); o[3] = f2bf(a[3]);
  o[4] = f2bf(b[0]); o[5] = f2bf(b[1]); o[6] = f2bf(b[2]); o[7] = f2bf(b[3]);
  *(u16x8*)(d + (size_t)r * FD + k8) = o;
}

// fp0[b][r] = b_ih0[r] + sum_k feat[b][k] * Wf[r][k]
__global__ __launch_bounds__(512, 2) void featpre_k(
    const unsigned short* __restrict__ Wf, const unsigned short* __restrict__ Fb,
    const float* __restrict__ bih0, float* __restrict__ fp0) {
  __shared__ float gl[2][4][16][64];
  int tid = threadIdx.x, lane = tid & 63, wid = tid >> 6;
  int lr = lane & 15, lg = lane >> 4;
  int sub = wid & 3, kh = wid >> 2;
  int rowblk = blockIdx.x << 6;
  size_t row0 = (size_t)rowblk + (sub << 4);
  f32x4 acc[4] = {};
  gemm16u(Wf + row0 * FD, Fb, FD, kh ? 512 : 0, kh ? 1024 : 512, lr, lg, acc);
  #pragma unroll
  for (int n0 = 0; n0 < 4; ++n0)
    #pragma unroll
    for (int e = 0; e < 4; ++e)
      gl[kh][sub][4 * lg + e][(n0 << 4) + lr] = acc[n0][e];
  __syncthreads();
  for (int n = tid; n < 4096; n += 512) {
    int i = n & 63, b = n >> 6;
    int r = rowblk + i;
    float v = gl[0][i >> 4][i & 15][b] + gl[1][i >> 4][i & 15][b] + bih0[r];
    fp0[(size_t)b * G4 + r] = v;
  }
}

// ih0T[r][j] = bf16( fp0[b][r] + W_v[r][tok(b,t)] ), j = b*31+t
__global__ __launch_bounds__(256) void gather_k(
    const float* __restrict__ Wih0, const int* __restrict__ caps,
    const float* __restrict__ fp0, unsigned short* __restrict__ ih0T) {
  __shared__ unsigned short wv[4][4000];
  int r0 = blockIdx.x << 2;
  for (int rr = 0; rr < 4; ++rr) {
    const float* src = Wih0 + (size_t)(r0 + rr) * LD0 + FD;
    for (int c4 = threadIdx.x; c4 < 1000; c4 += 256) {
      f32x4 v = *(const f32x4*)(src + c4 * 4);
      u16x4 o;
      o[0] = f2bf(v[0]); o[1] = f2bf(v[1]); o[2] = f2bf(v[2]); o[3] = f2bf(v[3]);
      *(u16x4*)(&wv[rr][c4 * 4]) = o;
    }
  }
  __syncthreads();
  for (int j = threadIdx.x; j < NJ; j += 256) {
    int b = j / TT, t = j - b * TT;
    int tok = caps[(b << 5) + t];
    f32x4 f = *(const f32x4*)(fp0 + (size_t)b * G4 + r0);
    #pragma unroll
    for (int rr = 0; rr < 4; ++rr)
      ih0T[(size_t)(r0 + rr) * NJ + j] = f2bf(f[rr] + bf2f(wv[rr][tok]));
  }
}

DEVINL size_t hpk(int r, int b) {          // packed h index [k8][64][8]
  return ((size_t)(r >> 3) * 64 + b) * 8 + (r & 7);
}

__global__ __launch_bounds__(1024, 4) void lstm_l0_k(
    const unsigned short* __restrict__ pWhh0, const unsigned short* __restrict__ hP_in,
    unsigned short* __restrict__ hP_out, float* __restrict__ c0,
    const unsigned short* __restrict__ ih0T, const float* __restrict__ bhh0, int t) {
  __shared__ float gl[2][4][16][64];
  int tid = threadIdx.x, lane = tid & 63, wid = tid >> 6;   // wid 0..15
  int lr = lane & 15, lg = lane >> 4;
  int gate = wid & 3, kq = wid >> 2;                        // 4-way K split
  int wg16 = blockIdx.x << 4;
  int kc0 = 31 * kq, kc1 = (kq == 3) ? KCT : kc0 + 31;
  const unsigned short* Wp = pWhh0 + ((size_t)(blockIdx.x * 4 + gate) * KCT) * 512;
  f32x4 acc[4] = {};
  gemmP(Wp, hP_in, kc0, kc1, lane, lr, lg, acc);
  if (kq < 2) {
    #pragma unroll
    for (int n0 = 0; n0 < 4; ++n0)
      #pragma unroll
      for (int e = 0; e < 4; ++e)
        gl[kq][gate][4 * lg + e][(n0 << 4) + lr] = acc[n0][e];
  }
  __syncthreads();
  if (kq >= 2) {
    #pragma unroll
    for (int n0 = 0; n0 < 4; ++n0)
      #pragma unroll
      for (int e = 0; e < 4; ++e)
        gl[kq - 2][gate][4 * lg + e][(n0 << 4) + lr] += acc[n0][e];
  }
  __syncthreads();
  int i = tid & 15, b = tid >> 4;                           // 1024 = 16 x 64
  int r = wg16 + i;
  size_t jo = (size_t)b * TT + t;
  float gi = gl[0][0][i][b] + gl[1][0][i][b] + bf2f(ih0T[(size_t)r * NJ + jo])              + bhh0[r];
  float gf = gl[0][1][i][b] + gl[1][1][i][b] + bf2f(ih0T[(size_t)(HDIM + r) * NJ + jo])     + bhh0[HDIM + r];
  float gg = gl[0][2][i][b] + gl[1][2][i][b] + bf2f(ih0T[(size_t)(2 * HDIM + r) * NJ + jo]) + bhh0[2 * HDIM + r];
  float go = gl[0][3][i][b] + gl[1][3][i][b] + bf2f(ih0T[(size_t)(3 * HDIM + r) * NJ + jo]) + bhh0[3 * HDIM + r];
  size_t ci = (size_t)b * HDIM + r;
  float cn = sigm(gf) * c0[ci] + sigm(gi) * tanh_(gg);
  float hn = sigm(go) * tanh_(cn);
  c0[ci] = cn;
  hP_out[hpk(r, b)] = f2bf(hn);
}

__global__ __launch_bounds__(1024, 4) void lstm_l1_k(
    const unsigned short* __restrict__ pWih1, const unsigned short* __restrict__ pWhh1,
    const unsigned short* __restrict__ hP0, const unsigned short* __restrict__ hP1_in,
    unsigned short* __restrict__ hP1_out, float* __restrict__ c1,
    const float* __restrict__ bih1, const float* __restrict__ bhh1,
    float* __restrict__ out, int t) {
  __shared__ float gl[2][4][16][64];
  int tid = threadIdx.x, lane = tid & 63, wid = tid >> 6;
  int lr = lane & 15, lg = lane >> 4;
  int gate = wid & 3, kq = wid >> 2;
  int wg16 = blockIdx.x << 4;
  int kc0 = 31 * kq, kc1 = (kq == 3) ? KCT : kc0 + 31;
  size_t wo = ((size_t)(blockIdx.x * 4 + gate) * KCT) * 512;
  f32x4 acc[4] = {};
  gemmP(pWih1 + wo, hP0,    kc0, kc1, lane, lr, lg, acc);
  gemmP(pWhh1 + wo, hP1_in, kc0, kc1, lane, lr, lg, acc);
  if (kq < 2) {
    #pragma unroll
    for (int n0 = 0; n0 < 4; ++n0)
      #pragma unroll
      for (int e = 0; e < 4; ++e)
        gl[kq][gate][4 * lg + e][(n0 << 4) + lr] = acc[n0][e];
  }
  __syncthreads();
  if (kq >= 2) {
    #pragma unroll
    for (int n0 = 0; n0 < 4; ++n0)
      #pragma unroll
      for (int e = 0; e < 4; ++e)
        gl[kq - 2][gate][4 * lg + e][(n0 << 4) + lr] += acc[n0][e];
  }
  __syncthreads();
  int i = tid & 15, b = tid >> 4;
  int r = wg16 + i;
  float gi = gl[0][0][i][b] + gl[1][0][i][b] + bih1[r]            + bhh1[r];
  float gf = gl[0][1][i][b] + gl[1][1][i][b] + bih1[HDIM + r]     + bhh1[HDIM + r];
  float gg = gl[0][2][i][b] + gl[1][2][i][b] + bih1[2 * HDIM + r] + bhh1[2 * HDIM + r];
  float go = gl[0][3][i][b] + gl[1][3][i][b] + bih1[3 * HDIM + r] + bhh1[3 * HDIM + r];
  size_t ci = (size_t)b * HDIM + r;
  float cn = sigm(gf) * c1[ci] + sigm(gi) * tanh_(gg);
  float hn = sigm(go) * tanh_(cn);
  c1[ci] = cn;
  hP1_out[hpk(r, b)] = f2bf(hn);
  out[(size_t)b * (32 * HDIM) + (size_t)(t + 1) * HDIM + r] = hn;
}

__global__ void sentinel_k(float* o) { o[0] = -123456.f; }

extern "C" void kernel_launch(void* const* d_in, const int* in_sizes, int n_in,
                              void* d_out, int out_size, void* d_ws, size_t ws_size,
                              hipStream_t stream) {
  (void)in_sizes; (void)n_in;
  const float* features = (const float*)d_in[0];
  const int*   captions = (const int*)d_in[1];
  const float* W_ih0    = (const float*)d_in[2];
  const float* W_hh0    = (const float*)d_in[3];
  const float* b_ih0    = (const float*)d_in[4];
  const float* b_hh0    = (const float*)d_in[5];
  const float* W_ih1    = (const float*)d_in[6];
  const float* W_hh1    = (const float*)d_in[7];
  const float* b_ih1    = (const float*)d_in[8];
  const float* b_hh1    = (const float*)d_in[9];
  float* out = (float*)d_out;

  char* w = (char*)d_ws;
  unsigned short* h0b   = (unsigned short*)(w);                 // 2 x 256000 elems, packed
  unsigned short* h1b   = (unsigned short*)(w + 1024000);
  float*          c0    = (float*)(w + 2048000);
  float*          c1    = (float*)(w + 3072000);
  unsigned short* pWhh0 = (unsigned short*)(w + 4096000);
  unsigned short* pWih1 = (unsigned short*)(w + 132096000);
  unsigned short* pWhh1 = (unsigned short*)(w + 260096000);
  unsigned short* bWf   = (unsigned short*)(w + 388096000);
  unsigned short* ih0T  = (unsigned short*)(w + 420864000);     // [16000][1984] bf16
  float*          fp0   = (float*)(w + 484352000);
  unsigned short* bFeat = (unsigned short*)(w + 488448000);
  const size_t NEED = 488579072;
  if (ws_size < NEED) { sentinel_k<<<1, 1, 0, stream>>>(out); return; }

  hipMemsetAsync(d_out, 0, (size_t)out_size * 4, stream);  // also provides out[:,0,:]=0
  hipMemsetAsync(w, 0, 4096000, stream);                   // h/c initial state = 0

  pack_k<<<31250, 256, 0, stream>>>(W_hh0, pWhh0);
  pack_k<<<31250, 256, 0, stream>>>(W_ih1, pWih1);
  pack_k<<<31250, 256, 0, stream>>>(W_hh1, pWhh1);
  to_bf16_k<<<32,    256, 0, stream>>>(features, bFeat, 65536L);
  wf_conv_k<<<8000,  256, 0, stream>>>(W_ih0, bWf);
  featpre_k<<<250,   512, 0, stream>>>(bWf, bFeat, b_ih0, fp0);
  gather_k<<<4000,   256, 0, stream>>>(W_ih0, captions, fp0, ih0T);

  for (int t = 0; t < TT; ++t) {
    unsigned short* h0_in  = h0b + (size_t)(t & 1) * 256000;
    unsigned short* h0_out = h0b + (size_t)((t + 1) & 1) * 256000;
    unsigned short* h1_in  = h1b + (size_t)(t & 1) * 256000;
    unsigned short* h1_out = h1b + (size_t)((t + 1) & 1) * 256000;
    lstm_l0_k<<<250, 1024, 0, stream>>>(pWhh0, h0_in, h0_out, c0, ih0T, b_hh0, t);
    lstm_l1_k<<<250, 1024, 0, stream>>>(pWih1, pWhh1, h0_out, h1_in, h1_out, c1,
                                        b_ih1, b_hh1, out, t);
  }
}